// Round 24
// baseline (414.651 us; speedup 1.0000x reference)
//
#include <hip/hip_runtime.h>
#include <hip/hip_bf16.h>
#include <stdint.h>

#define NTOK 4096   // B*T = 2*2048
#define CD   1024
#define HD   4096
#define NE   8
#define ECAP 1536   // fixed slots per expert (n_e ~ 1024+-30, +17 sigma)

typedef __attribute__((ext_vector_type(8))) short bf16x8;
typedef __attribute__((ext_vector_type(4))) float f32x4;
typedef __attribute__((ext_vector_type(4))) unsigned short us4;
typedef __attribute__((ext_vector_type(8))) unsigned short us8;

#define BARR() asm volatile("s_barrier" ::: "memory")
#define VM2() asm volatile("s_waitcnt vmcnt(2)" ::: "memory")
#define VM0() asm volatile("s_waitcnt vmcnt(0)" ::: "memory")

__device__ __forceinline__ unsigned short f2bf(float f){
  __hip_bfloat16 h = __float2bfloat16(f);
  return *reinterpret_cast<unsigned short*>(&h);
}

// ---------------- FUSED pre-pass: router+direct-scatter (bid<1024) | w1 transpose ----------------
// w2's transpose rides inside GEMM1's dispatch (r19-verified overlap): here router + w1t only.
__global__ __launch_bounds__(256) void fused_pre(
    const float* __restrict__ x, const float* __restrict__ rw,
    const float* __restrict__ w1,
    unsigned short* __restrict__ x_bf, int* __restrict__ counts,
    int* __restrict__ g_tok, float* __restrict__ g_w,
    unsigned short* __restrict__ w1t){
  __shared__ float tile[64][65];         // transpose only (16.64KB)
  int bid = blockIdx.x;
  int tid = threadIdx.x;

  if (bid < NTOK/4){
    // ---------- router: logits (fp64 accum), softmax, top-2, renorm; x -> bf16; direct scatter ----------
    int l = tid & 63, w = tid >> 6;
    int n = bid*4 + w;

    float4 xv[4];
    #pragma unroll
    for (int j = 0; j < 4; ++j)
      xv[j] = ((const float4*)(x + (size_t)n*CD))[l + j*64];

    #pragma unroll
    for (int j = 0; j < 4; ++j){
      us4 o; o.x = f2bf(xv[j].x); o.y = f2bf(xv[j].y); o.z = f2bf(xv[j].z); o.w = f2bf(xv[j].w);
      *(us4*)(x_bf + (size_t)n*CD + l*4 + j*256) = o;
    }

    const float4* rwv = (const float4*)rw;   // 32KB total: L1/L2-resident
    double le[NE];
    #pragma unroll
    for (int e = 0; e < NE; ++e){
      double p = 0.0;
      #pragma unroll
      for (int j = 0; j < 4; ++j){
        float4 rv = rwv[e*(CD/4) + l + j*64];
        p += (double)xv[j].x*rv.x + (double)xv[j].y*rv.y + (double)xv[j].z*rv.z + (double)xv[j].w*rv.w;
      }
      #pragma unroll
      for (int d = 32; d >= 1; d >>= 1) p += __shfl_xor(p, d);
      le[e] = p;
    }
    if (l == 0){
      double m = le[0];
      #pragma unroll
      for (int e = 1; e < NE; ++e) m = le[e] > m ? le[e] : m;
      double pe[NE];
      #pragma unroll
      for (int e = 0; e < NE; ++e) pe[e] = exp(le[e]-m);
      int i0 = 0;
      #pragma unroll
      for (int e = 1; e < NE; ++e) if (pe[e] > pe[i0]) i0 = e;   // strict >: ties -> lower idx (lax.top_k)
      int i1 = (i0 == 0) ? 1 : 0;
      #pragma unroll
      for (int e = 0; e < NE; ++e){ if (e == i0) continue; if (pe[e] > pe[i1]) i1 = e; }
      double w0 = pe[i0], w1v = pe[i1], wsum = w0 + w1v;
      int p0 = atomicAdd(&counts[i0], 1);
      g_tok[i0*ECAP + p0] = n;  g_w[i0*ECAP + p0] = (float)(w0/wsum);
      int p1 = atomicAdd(&counts[i1], 1);
      g_tok[i1*ECAP + p1] = n;  g_w[i1*ECAP + p1] = (float)(w1v/wsum);
    }
    return;
  }

  // ---------- w1 transpose + fp32->bf16: [E][CD][HD] -> w1t [E][HD][CD] ----------
  int t = bid - NTOK/4;                  // 8192 tiles
  int xx = t & 63, yy = (t >> 6) & 15, e = t >> 10;
  const float* ip = w1 + (size_t)e*CD*HD;
  unsigned short* op = w1t + (size_t)e*CD*HD;
  int s0 = xx*64, r0 = yy*64;
  #pragma unroll
  for (int i = 0; i < 4; ++i){
    int lin = i*256 + tid;
    int rr = lin >> 4, c4 = lin & 15;
    float4 v = *(const float4*)(ip + (size_t)(r0+rr)*HD + s0 + c4*4);
    tile[rr][c4*4+0] = v.x; tile[rr][c4*4+1] = v.y;
    tile[rr][c4*4+2] = v.z; tile[rr][c4*4+3] = v.w;
  }
  __syncthreads();
  #pragma unroll
  for (int i = 0; i < 4; ++i){
    int lin = i*256 + tid;
    int ss = lin >> 4, rq = lin & 15;
    us4 o;
    o.x = f2bf(tile[rq*4+0][ss]);
    o.y = f2bf(tile[rq*4+1][ss]);
    o.z = f2bf(tile[rq*4+2][ss]);
    o.w = f2bf(tile[rq*4+3][ss]);
    *(us4*)(op + (size_t)(s0+ss)*CD + r0 + rq*4) = o;
  }
}

// ---------------- grouped GEMM, 24-WAVE RING-3 + EXPERT-PER-XCD (+ optional fused w2t) ----------------
// r16-verified engine: 128x128 tile, BK=32, 8 waves of 64x32, 3-buf ring, counted vmcnt,
// 3 blocks/CU = 24 waves; XCD k = p&7 owns expert k, y-inner. Slot layout g_base = e*ECAP.
// FUSE=1 (GEMM1): 1D grid in groups of 40 = 24 GEMM + 16 w2-transpose blocks (both %8==0, so
// GEMM p&7 == bid&7 == XCD). Transpose sub-block: 512 thr, 2x[64][65] dbuf (33KB<=49KB),
// 4 tiles, 1 sync/tile (r19-verified). EPI 0: h=gelu(x@w1t^T) bf16.  EPI 1: atomics into out.
template<int KLEN, int SPLITK, int EPI, int FUSE>
__global__ __launch_bounds__(512, 6) void gemm_ring3(
    const unsigned short* __restrict__ A_src,
    const unsigned short* __restrict__ B_src,
    unsigned short* __restrict__ h_out,
    float* __restrict__ outp,
    const int* __restrict__ g_tok,
    const float* __restrict__ g_w,
    const int* __restrict__ counts,
    int NDIM, int KSTRIDE, int GN, int GY,
    const float* __restrict__ w2src, unsigned short* __restrict__ w2dst){
  constexpr int NT = KLEN/32;
  constexpr int ZPX = (NE*SPLITK)/8;           // z-slabs per XCD (GEMM1: 1, GEMM2: 2)
  __shared__ alignas(128) char lds[49152];     // GEMM: 3 bufs x 16KB | transpose: 2 x [64][65] f32

  int bid = blockIdx.x + gridDim.x*(blockIdx.y + gridDim.y*blockIdx.z);
  int tid = threadIdx.x;
  int p;
  if (FUSE){
    int gp = bid/40, rm = bid%40;
    if (rm >= 24){
      // ---------- w2 transpose: [E][HD][CD] -> w2t [E][CD][HD]; 2048 blocks x 4 tiles ----------
      typedef float ftile_t[64][65];
      ftile_t* tiles = (ftile_t*)lds;
      int base = (gp*16 + (rm - 24)) * 4;      // 8192 tiles = 8e x 64y x 16x
      float4 v[2];
      auto LOADREGS = [&](int t){
        int xx = t & 15, yy = (t >> 4) & 63, e = t >> 10;
        const float* ip = w2src + (size_t)e*CD*HD;
        #pragma unroll
        for (int i = 0; i < 2; ++i){
          int lin = i*512 + tid;
          v[i] = *(const float4*)(ip + (size_t)(yy*64 + (lin>>4))*CD + xx*64 + (lin&15)*4);
        }
      };
      LOADREGS(base);
      #pragma unroll 1
      for (int it = 0; it < 4; ++it){
        float (*tile)[65] = tiles[it & 1];
        #pragma unroll
        for (int i = 0; i < 2; ++i){
          int lin = i*512 + tid;
          int rr2 = lin >> 4, c4 = lin & 15;
          tile[rr2][c4*4+0] = v[i].x; tile[rr2][c4*4+1] = v[i].y;
          tile[rr2][c4*4+2] = v[i].z; tile[rr2][c4*4+3] = v[i].w;
        }
        if (it < 3) LOADREGS(base + it + 1);
        __syncthreads();
        int t = base + it;
        int xx = t & 15, yy = (t >> 4) & 63, e = t >> 10;
        unsigned short* op = w2dst + (size_t)e*CD*HD;
        int ss = tid >> 3, rq8 = tid & 7;
        us8 o;
        #pragma unroll
        for (int j = 0; j < 8; ++j)
          o[j] = f2bf(tile[rq8*8+j][ss]);
        *(us8*)(op + (size_t)(xx*64+ss)*HD + yy*64 + rq8*8) = o;
      }
      return;
    }
    p = gp*24 + rm;                            // p&7 == bid&7 == XCD (24,16 both %8==0)
  } else {
    p = bid;
  }

  // ---- expert-per-XCD decode ----
  int k8 = p & 7;                              // XCD (round-robin dispatch premise)
  int i  = p >> 3;
  int s  = i / (GN*GY);
  int r  = i - s*(GN*GY);
  int y  = r % GY;                             // y inner: B-panel sharers adjacent in time
  int xb = r / GY;
  int z  = k8*ZPX + s;

  int e  = (SPLITK == 1) ? z : (z / SPLITK);
  int kz = (SPLITK == 1) ? 0 : (z % SPLITK);
  int n_e = counts[e];
  int m0 = y*128;
  if (m0 >= n_e) return;
  int n0 = xb*128;
  int g_base = e*ECAP;
  int kstart = kz*KLEN;

  int l = tid & 63, w = tid >> 6;              // 8 waves
  int wr = w >> 2, wc = w & 3;                 // wave tile: rows wr*64, cols wc*32
  int lrow = l & 15, q = l >> 4;

  // staging pointers: 2 insts/thread cover A (8KB) then B (8KB) of one K-tile
  const unsigned short* src[2];
  uint32_t dst[2];
  #pragma unroll
  for (int ii = 0; ii < 2; ++ii){
    int g = ii*512 + tid;                // 0..1023
    bool isA = g < 512;
    int gg = isA ? g : (g - 512);
    int row = gg >> 2, c = gg & 3;
    int cs = c ^ (row & 3) ^ ((row >> 2) & 3);   // source swizzle; LDS stays linear
    if (isA){
      int rg = m0 + row; if (rg > n_e-1) rg = n_e-1;   // clamp partial tile (rows discarded at epilogue)
      size_t arow;
      if (EPI == 0) arow = (size_t)g_tok[g_base + rg];  // gather token rows of x
      else          arow = (size_t)(g_base + rg);       // dense slot rows of h
      src[ii] = A_src + arow*(size_t)KSTRIDE + kstart + cs*8;
    } else {
      src[ii] = B_src + ((size_t)e*NDIM + n0 + row)*(size_t)KSTRIDE + kstart + cs*8;
    }
    dst[ii] = (uint32_t)g*16u;
  }

  auto STAGE = [&](int tt, uint32_t bufoff){
    #pragma unroll
    for (int ii = 0; ii < 2; ++ii)
      __builtin_amdgcn_global_load_lds(
        (const __attribute__((address_space(1))) void*)(src[ii] + (size_t)tt*32),
        (__attribute__((address_space(3))) void*)&lds[dst[ii] + bufoff], 16, 0, 0);
  };

  // fragment read offsets: byte = row*64 + 16*(q ^ X(row)), X = (row&3)^((row>>2)&3); +8192 for B
  uint32_t a_off[4], b_off[2];
  #pragma unroll
  for (int m = 0; m < 4; ++m){
    int ra = wr*64 + m*16 + lrow;
    int Xa = (ra & 3) ^ ((ra >> 2) & 3);
    a_off[m] = (uint32_t)(ra*64) + 16u*(uint32_t)(q ^ Xa);
  }
  #pragma unroll
  for (int n = 0; n < 2; ++n){
    int rb = wc*32 + n*16 + lrow;
    int Xb = (rb & 3) ^ ((rb >> 2) & 3);
    b_off[n] = 8192u + (uint32_t)(rb*64) + 16u*(uint32_t)(q ^ Xb);
  }

  f32x4 acc[4][2] = {};

  // prologue: tiles 0,1 -> bufs 0,1 (4 loads in flight)
  STAGE(0, 0u); STAGE(1, 16384u);

  uint32_t ro = 0u;          // read buf offset, rotates 0,16K,32K
  uint32_t so = 32768u;      // stage buf offset for tile kt+2
  #pragma unroll 1
  for (int kt = 0; kt < NT; ++kt){
    if (kt < NT-1) { VM2(); } else { VM0(); }   // own tile-kt loads landed
    BARR();                                     // all waves' tile-kt slices visible; buf so free
    if (kt + 2 < NT) STAGE(kt + 2, so);
    bf16x8 av[4], bv[2];
    #pragma unroll
    for (int m = 0; m < 4; ++m)
      av[m] = *(const bf16x8*)&lds[a_off[m] + ro];
    #pragma unroll
    for (int n = 0; n < 2; ++n)
      bv[n] = *(const bf16x8*)&lds[b_off[n] + ro];
    __builtin_amdgcn_s_setprio(1);
    #pragma unroll
    for (int m = 0; m < 4; ++m)
      #pragma unroll
      for (int n = 0; n < 2; ++n)
        acc[m][n] = __builtin_amdgcn_mfma_f32_16x16x32_bf16(av[m], bv[n], acc[m][n], 0, 0, 0);
    __builtin_amdgcn_s_setprio(0);
    ro = (ro == 32768u) ? 0u : ro + 16384u;
    so = (so == 32768u) ? 0u : so + 16384u;
  }

  // C/D layout (verified m89): col = lane&15, row = (lane>>4)*4 + j
  if (EPI == 0){
    #pragma unroll
    for (int m = 0; m < 4; ++m){
      #pragma unroll
      for (int jj = 0; jj < 4; ++jj){
        int rr = m0 + wr*64 + m*16 + q*4 + jj;
        if (rr < n_e){
          unsigned short* hp = h_out + (size_t)(g_base + rr)*NDIM + n0 + wc*32 + lrow;
          #pragma unroll
          for (int n = 0; n < 2; ++n){
            float v = acc[m][n][jj];
            v = 0.5f*v*(1.0f + erff(v*0.70710678118654752f));   // exact GELU
            hp[n*16] = f2bf(v);
          }
        }
      }
    }
  } else {
    #pragma unroll
    for (int m = 0; m < 4; ++m){
      #pragma unroll
      for (int jj = 0; jj < 4; ++jj){
        int rr = m0 + wr*64 + m*16 + q*4 + jj;
        if (rr < n_e){
          int slot = g_base + rr;
          int tt = g_tok[slot];
          float wgt = g_w[slot];
          float* op = outp + (size_t)tt*NDIM + n0 + wc*32 + lrow;
          #pragma unroll
          for (int n = 0; n < 2; ++n)
            atomicAdd(op + n*16, wgt*acc[m][n][jj]);
        }
      }
    }
  }
}

extern "C" void kernel_launch(void* const* d_in, const int* in_sizes, int n_in,
                              void* d_out, int out_size, void* d_ws, size_t ws_size,
                              hipStream_t stream) {
  const float* x  = (const float*)d_in[0];
  const float* rw = (const float*)d_in[1];
  const float* w1 = (const float*)d_in[2];
  const float* w2 = (const float*)d_in[3];

  size_t off = 0;
  auto alloc = [&](size_t sz) -> char* {
    char* p = (char*)d_ws + off;
    off += (sz + 255) & ~(size_t)255;
    return p;
  };
  unsigned short* x_bf = (unsigned short*)alloc((size_t)NTOK*CD*2);     // 8.4 MB
  unsigned short* w1t  = (unsigned short*)alloc((size_t)NE*CD*HD*2);    // 67 MB  [E][H][C]
  unsigned short* w2t  = (unsigned short*)alloc((size_t)NE*CD*HD*2);    // 67 MB  [E][C][H]
  unsigned short* hbuf = (unsigned short*)alloc((size_t)NE*ECAP*HD*2);  // 101 MB [e*ECAP+slot][H]
  int*   counts = (int*)alloc(64);
  int*   g_tok  = (int*)alloc(NE*ECAP*4);
  float* g_w    = (float*)alloc(NE*ECAP*4);
  (void)ws_size; (void)in_sizes; (void)n_in; (void)out_size;

  hipMemsetAsync(d_out, 0, (size_t)NTOK*CD*4, stream);
  hipMemsetAsync(counts, 0, 64, stream);

  // fused: router+direct-scatter (1024 blocks) + w1 transpose (8192 blocks)
  fused_pre<<<dim3(NTOK/4 + 8192), dim3(256), 0, stream>>>(
      x, rw, w1, x_bf, counts, g_tok, g_w, w1t);

  // GEMM1 (+ fused w2 transpose): 5120 blocks = 128 groups x (24 GEMM + 16 w2t)
  gemm_ring3<CD, 1, 0, 1><<<dim3(5120), dim3(512), 0, stream>>>(
      x_bf, w1t, hbuf, (float*)nullptr, g_tok, g_w, counts, HD, CD, 32, 12, w2, w2t);
  // GEMM2: out[token] += w * (h @ w2t^T)   M=n_e, N=C (1024), K=4096 split-K x2; 8x12x16
  gemm_ring3<HD/2, 2, 1, 0><<<dim3(8, 12, 16), dim3(512), 0, stream>>>(
      hbuf, w2t, (unsigned short*)nullptr, (float*)d_out, g_tok, g_w, counts, CD, HD, 8, 12,
      (const float*)nullptr, (unsigned short*)nullptr);
}